// Round 1
// baseline (947.478 us; speedup 1.0000x reference)
//
#include <hip/hip_runtime.h>
#include <hip/hip_bf16.h>
#include <hip/hip_fp16.h>

typedef __attribute__((ext_vector_type(4))) float f32x4;
typedef __attribute__((ext_vector_type(8))) __bf16 bf16x8;
typedef __attribute__((ext_vector_type(8))) unsigned short u16x8;
typedef unsigned int u32;
typedef unsigned short u16;

// ---------- helpers ----------
__device__ __forceinline__ void gload_lds16(const void* g, void* l) {
  __builtin_amdgcn_global_load_lds((const u32 __attribute__((address_space(1)))*)g,
                                   (u32 __attribute__((address_space(3)))*)l, 16, 0, 0);
}
__device__ __forceinline__ u16 f2bf(float f) {           // exact for small integers
  union { float f; u32 u; } c; c.f = f; return (u16)(c.u >> 16);
}
__device__ __forceinline__ float h2f(u16 u) { return __half2float(__ushort_as_half(u)); }
__device__ __forceinline__ u16  f2h(float f){ return __half_as_ushort(__float2half_rn(f)); }

// ---------- 1. per-token RMS-norm + absmax int8 quant of x (stored as bf16 ints) ----------
__global__ __launch_bounds__(256) void quant_x_kernel(const float* __restrict__ x,
    u16* __restrict__ qx, float* __restrict__ invs) {
  const int D = 2048;
  int row = blockIdx.x, tid = threadIdx.x;
  const float* xr = x + (size_t)row * D;
  float4 a = ((const float4*)xr)[tid * 2], b = ((const float4*)xr)[tid * 2 + 1];
  float v[8] = {a.x, a.y, a.z, a.w, b.x, b.y, b.z, b.w};
  double ss = 0; float mx = 0.0f;
#pragma unroll
  for (int i = 0; i < 8; i++) { ss += (double)v[i] * v[i]; mx = fmaxf(mx, fabsf(v[i])); }
  __shared__ double sd[256]; __shared__ float sf[256];
  sd[tid] = ss; sf[tid] = mx; __syncthreads();
  for (int o = 128; o > 0; o >>= 1) {
    if (tid < o) { sd[tid] += sd[tid + o]; sf[tid] = fmaxf(sf[tid], sf[tid + o]); }
    __syncthreads();
  }
  __shared__ float bn, bs;
  if (tid == 0) {
    float n = fmaxf((float)sqrt(sd[0]), 1e-12f);
    float amax = sf[0] * (sqrtf((float)D) / n);
    float cl = fmaxf(amax, 1e-5f);
    bn = n; bs = 127.0f / cl;
    invs[row] = cl / 127.0f;
  }
  __syncthreads();
  float n = bn, s = bs, sq = sqrtf((float)D);
  u16x8 q;
#pragma unroll
  for (int i = 0; i < 8; i++) {
    float xn = (v[i] / n) * sq;
    float r = rintf(xn * s);
    r = fminf(fmaxf(r, -128.0f), 127.0f);
    q[i] = f2bf(r);
  }
  *(u16x8*)&qx[(size_t)row * D + tid * 8] = q;
}

// ---------- 2. deterministic sum(|w|) partials ----------
__global__ __launch_bounds__(256) void absum_partial(const float* __restrict__ w,
    double* __restrict__ part, int n4) {
  int tid = threadIdx.x;
  double s = 0;
  for (int i = blockIdx.x * 256 + tid; i < n4; i += gridDim.x * 256) {
    float4 v = ((const float4*)w)[i];
    s += (double)fabsf(v.x) + (double)fabsf(v.y) + (double)fabsf(v.z) + (double)fabsf(v.w);
  }
  __shared__ double sd[256];
  sd[tid] = s; __syncthreads();
  for (int o = 128; o > 0; o >>= 1) { if (tid < o) sd[tid] += sd[tid + o]; __syncthreads(); }
  if (tid == 0) part[blockIdx.x] = sd[0];
}

__global__ __launch_bounds__(256) void wscale_final(const double* __restrict__ part,
    float* __restrict__ wsc) {
  int tid = threadIdx.x;
  __shared__ double sd[256];
  sd[tid] = part[tid] + part[tid + 256]; __syncthreads();
  for (int o = 128; o > 0; o >>= 1) { if (tid < o) sd[tid] += sd[tid + o]; __syncthreads(); }
  double s1 = sd[0]; __syncthreads();
  sd[tid] = part[512 + tid] + part[768 + tid]; __syncthreads();
  for (int o = 128; o > 0; o >>= 1) { if (tid < o) sd[tid] += sd[tid + o]; __syncthreads(); }
  if (tid == 0) {
    float m1 = (float)(s1 / 16777216.0);
    float m2 = (float)(sd[0] / 16777216.0);
    float d1 = fmaxf(m1, 1e-5f), d2 = fmaxf(m2, 1e-5f);
    wsc[0] = 1.0f / d1; wsc[1] = d1; wsc[2] = 1.0f / d2; wsc[3] = d2;
  }
}

// ---------- 3. ternary weight quant (stored as bf16 {-1,0,1}) ----------
__global__ __launch_bounds__(256) void quant_w_kernel(const float* __restrict__ w,
    u16* __restrict__ q, const float* __restrict__ wsc, int widx, int n4) {
  float s = wsc[widx];
  for (int i = blockIdx.x * 256 + threadIdx.x; i < n4; i += gridDim.x * 256) {
    float4 v = ((const float4*)w)[i];
    ushort4 o;
    o.x = f2bf(fminf(fmaxf(rintf(v.x * s), -1.0f), 1.0f));
    o.y = f2bf(fminf(fmaxf(rintf(v.y * s), -1.0f), 1.0f));
    o.z = f2bf(fminf(fmaxf(rintf(v.z * s), -1.0f), 1.0f));
    o.w = f2bf(fminf(fmaxf(rintf(v.w * s), -1.0f), 1.0f));
    ((ushort4*)q)[i] = o;
  }
}

// ---------- 4. GEMM (A[M][K] x B[N][K], both bf16-int, K-contiguous), m97 structure ----------
// EPI==0: dequant + exact GELU -> f16 store.  EPI==1: dequant -> f32 store.
template <int EPI>
__global__ __launch_bounds__(256) void gemm_bt(const u16* __restrict__ A, const u16* __restrict__ B,
    int M, int N, int K, const float* __restrict__ rowscale, const float* __restrict__ wsc,
    int widx, void* __restrict__ outp) {
  __shared__ u16 lA[128 * 32], lB[128 * 32];
  int tid = threadIdx.x;
  int bn = blockIdx.x, bm = blockIdx.y;
  int lane = tid & 63, wid = tid >> 6;
  int wm = wid >> 1, wn = wid & 1;
  int lhi = lane >> 4, llo = lane & 15;
  f32x4 acc[4][4];
#pragma unroll
  for (int i = 0; i < 4; i++)
#pragma unroll
    for (int j = 0; j < 4; j++) acc[i][j] = (f32x4){0.f, 0.f, 0.f, 0.f};

  const u16* Ag0 = A + (size_t)(bm * 128 + (tid >> 2)) * K + (tid & 3) * 8;
  const u16* Bg0 = B + (size_t)(bn * 128 + (tid >> 2)) * K + (tid & 3) * 8;

  for (int k0 = 0; k0 < K; k0 += 32) {
    gload_lds16(Ag0 + k0, &lA[tid * 8]);
    gload_lds16(Ag0 + (size_t)64 * K + k0, &lA[2048 + tid * 8]);
    gload_lds16(Bg0 + k0, &lB[tid * 8]);
    gload_lds16(Bg0 + (size_t)64 * K + k0, &lB[2048 + tid * 8]);
    __syncthreads();
    bf16x8 af[4], bfr[4];
#pragma unroll
    for (int i = 0; i < 4; i++) af[i] = *(const bf16x8*)&lA[(wm * 64 + i * 16 + llo) * 32 + lhi * 8];
#pragma unroll
    for (int j = 0; j < 4; j++) bfr[j] = *(const bf16x8*)&lB[(wn * 64 + j * 16 + llo) * 32 + lhi * 8];
#pragma unroll
    for (int i = 0; i < 4; i++)
#pragma unroll
      for (int j = 0; j < 4; j++)
        acc[i][j] = __builtin_amdgcn_mfma_f32_16x16x32_bf16(af[i], bfr[j], acc[i][j], 0, 0, 0);
    __syncthreads();
  }

  float wdeq = wsc[widx];
  int r0 = bm * 128 + wm * 64 + lhi * 4;
  int c0 = bn * 128 + wn * 64 + llo;
#pragma unroll
  for (int i = 0; i < 4; i++) {
#pragma unroll
    for (int reg = 0; reg < 4; reg++) {
      int r = r0 + i * 16 + reg;
      float deq = rowscale[r] * wdeq;
#pragma unroll
      for (int j = 0; j < 4; j++) {
        int c = c0 + j * 16;
        float val = acc[i][j][reg] * deq;
        if (EPI == 0) {
          float g = 0.5f * val * (1.0f + erff(val * 0.70710678118654752440f));
          ((u16*)outp)[(size_t)r * N + c] = f2h(g);
        } else {
          ((float*)outp)[(size_t)r * N + c] = val;
        }
      }
    }
  }
}

// ---------- 5. per-row norm + quant of h (f16 in, bf16-int out, in place) ----------
__global__ __launch_bounds__(256) void quant_h_kernel(u16* __restrict__ h, float* __restrict__ invs) {
  const int D = 8192;
  int row = blockIdx.x, tid = threadIdx.x;
  u16* hr = h + (size_t)row * D;
  float v[32];
#pragma unroll
  for (int j = 0; j < 4; j++) {
    u16x8 u = *(const u16x8*)&hr[j * 2048 + tid * 8];
#pragma unroll
    for (int e = 0; e < 8; e++) v[j * 8 + e] = h2f(u[e]);
  }
  double ss = 0; float mx = 0.0f;
#pragma unroll
  for (int i = 0; i < 32; i++) { ss += (double)v[i] * v[i]; mx = fmaxf(mx, fabsf(v[i])); }
  __shared__ double sd[256]; __shared__ float sf[256];
  sd[tid] = ss; sf[tid] = mx; __syncthreads();
  for (int o = 128; o > 0; o >>= 1) {
    if (tid < o) { sd[tid] += sd[tid + o]; sf[tid] = fmaxf(sf[tid], sf[tid + o]); }
    __syncthreads();
  }
  __shared__ float bn, bs;
  if (tid == 0) {
    float n = fmaxf((float)sqrt(sd[0]), 1e-12f);
    float amax = sf[0] * (sqrtf((float)D) / n);
    float cl = fmaxf(amax, 1e-5f);
    bn = n; bs = 127.0f / cl;
    invs[row] = cl / 127.0f;
  }
  __syncthreads();
  float n = bn, s = bs, sq = sqrtf((float)D);
#pragma unroll
  for (int j = 0; j < 4; j++) {
    u16x8 q;
#pragma unroll
    for (int e = 0; e < 8; e++) {
      float xn = (v[j * 8 + e] / n) * sq;
      float r = rintf(xn * s);
      r = fminf(fmaxf(r, -128.0f), 127.0f);
      q[e] = f2bf(r);
    }
    *(u16x8*)&hr[j * 2048 + tid * 8] = q;
  }
}

// ---------- launch ----------
extern "C" void kernel_launch(void* const* d_in, const int* in_sizes, int n_in,
                              void* d_out, int out_size, void* d_ws, size_t ws_size,
                              hipStream_t stream) {
  const float* x  = (const float*)d_in[0];   // [4,2048,2048] f32
  const float* w1 = (const float*)d_in[1];   // [8192,2048]   f32
  const float* w2 = (const float*)d_in[2];   // [2048,8192]   f32

  char* ws = (char*)d_ws;
  u16*    qx     = (u16*)(ws + 0);             // 8192x2048 bf16  (32 MB)
  u16*    w1q    = (u16*)(ws + 33554432);      // 8192x2048 bf16  (32 MB)
  u16*    w2q    = (u16*)(ws + 67108864);      // 2048x8192 bf16  (32 MB)
  u16*    h      = (u16*)(ws + 100663296);     // 8192x8192 f16 -> bf16-int (128 MB)
  float*  invs_x = (float*)(ws + 234881024);   // 8192 f32
  float*  invs_h = (float*)(ws + 234913792);   // 8192 f32
  double* part   = (double*)(ws + 234946560);  // 1024 f64
  float*  wsc    = (float*)(ws + 234954752);   // 4 f32: {1/d1, d1, 1/d2, d2}

  quant_x_kernel<<<8192, 256, 0, stream>>>(x, qx, invs_x);
  absum_partial<<<512, 256, 0, stream>>>(w1, part, 4194304);
  absum_partial<<<512, 256, 0, stream>>>(w2, part + 512, 4194304);
  wscale_final<<<1, 256, 0, stream>>>(part, wsc);
  quant_w_kernel<<<2048, 256, 0, stream>>>(w1, w1q, wsc, 0, 4194304);
  quant_w_kernel<<<2048, 256, 0, stream>>>(w2, w2q, wsc, 2, 4194304);
  gemm_bt<0><<<dim3(64, 64), 256, 0, stream>>>(qx, w1q, 8192, 8192, 2048, invs_x, wsc, 1, (void*)h);
  quant_h_kernel<<<8192, 256, 0, stream>>>(h, invs_h);
  gemm_bt<1><<<dim3(16, 64), 256, 0, stream>>>(h, w2q, 8192, 2048, 8192, invs_h, wsc, 3, d_out);
}

// Round 2
// 672.209 us; speedup vs baseline: 1.4095x; 1.4095x over previous
//
#include <hip/hip_runtime.h>
#include <hip/hip_bf16.h>
#include <hip/hip_fp16.h>

typedef __attribute__((ext_vector_type(4))) float f32x4;
typedef __attribute__((ext_vector_type(8))) __bf16 bf16x8;
typedef __attribute__((ext_vector_type(8))) unsigned short u16x8;
typedef unsigned int u32;
typedef unsigned short u16;

#define BAR() asm volatile("s_barrier" ::: "memory")

// ---------- helpers ----------
__device__ __forceinline__ void gload_lds16(const void* g, void* l) {
  __builtin_amdgcn_global_load_lds((const u32 __attribute__((address_space(1)))*)g,
                                   (u32 __attribute__((address_space(3)))*)l, 16, 0, 0);
}
__device__ __forceinline__ u16 f2bf(float f) {           // exact for small integers
  union { float f; u32 u; } c; c.f = f; return (u16)(c.u >> 16);
}
__device__ __forceinline__ float h2f(u16 u) { return __half2float(__ushort_as_half(u)); }
__device__ __forceinline__ u16  f2h(float f){ return __half_as_ushort(__float2half_rn(f)); }

// ---------- 1. per-token RMS-norm + absmax int8 quant of x (stored as bf16 ints) ----------
__global__ __launch_bounds__(256) void quant_x_kernel(const float* __restrict__ x,
    u16* __restrict__ qx, float* __restrict__ invs) {
  const int D = 2048;
  int row = blockIdx.x, tid = threadIdx.x;
  const float* xr = x + (size_t)row * D;
  float4 a = ((const float4*)xr)[tid * 2], b = ((const float4*)xr)[tid * 2 + 1];
  float v[8] = {a.x, a.y, a.z, a.w, b.x, b.y, b.z, b.w};
  double ss = 0; float mx = 0.0f;
#pragma unroll
  for (int i = 0; i < 8; i++) { ss += (double)v[i] * v[i]; mx = fmaxf(mx, fabsf(v[i])); }
  __shared__ double sd[256]; __shared__ float sf[256];
  sd[tid] = ss; sf[tid] = mx; __syncthreads();
  for (int o = 128; o > 0; o >>= 1) {
    if (tid < o) { sd[tid] += sd[tid + o]; sf[tid] = fmaxf(sf[tid], sf[tid + o]); }
    __syncthreads();
  }
  __shared__ float bn, bs;
  if (tid == 0) {
    float n = fmaxf((float)sqrt(sd[0]), 1e-12f);
    float amax = sf[0] * (sqrtf((float)D) / n);
    float cl = fmaxf(amax, 1e-5f);
    bn = n; bs = 127.0f / cl;
    invs[row] = cl / 127.0f;
  }
  __syncthreads();
  float n = bn, s = bs, sq = sqrtf((float)D);
  u16x8 q;
#pragma unroll
  for (int i = 0; i < 8; i++) {
    float xn = (v[i] / n) * sq;
    float r = rintf(xn * s);
    r = fminf(fmaxf(r, -128.0f), 127.0f);
    q[i] = f2bf(r);
  }
  *(u16x8*)&qx[(size_t)row * D + tid * 8] = q;
}

// ---------- 2. deterministic sum(|w|) partials ----------
__global__ __launch_bounds__(256) void absum_partial(const float* __restrict__ w,
    double* __restrict__ part, int n4) {
  int tid = threadIdx.x;
  double s = 0;
  for (int i = blockIdx.x * 256 + tid; i < n4; i += gridDim.x * 256) {
    float4 v = ((const float4*)w)[i];
    s += (double)fabsf(v.x) + (double)fabsf(v.y) + (double)fabsf(v.z) + (double)fabsf(v.w);
  }
  __shared__ double sd[256];
  sd[tid] = s; __syncthreads();
  for (int o = 128; o > 0; o >>= 1) { if (tid < o) sd[tid] += sd[tid + o]; __syncthreads(); }
  if (tid == 0) part[blockIdx.x] = sd[0];
}

__global__ __launch_bounds__(256) void wscale_final(const double* __restrict__ part,
    float* __restrict__ wsc) {
  int tid = threadIdx.x;
  __shared__ double sd[256];
  sd[tid] = part[tid] + part[tid + 256]; __syncthreads();
  for (int o = 128; o > 0; o >>= 1) { if (tid < o) sd[tid] += sd[tid + o]; __syncthreads(); }
  double s1 = sd[0]; __syncthreads();
  sd[tid] = part[512 + tid] + part[768 + tid]; __syncthreads();
  for (int o = 128; o > 0; o >>= 1) { if (tid < o) sd[tid] += sd[tid + o]; __syncthreads(); }
  if (tid == 0) {
    float m1 = (float)(s1 / 16777216.0);
    float m2 = (float)(sd[0] / 16777216.0);
    float d1 = fmaxf(m1, 1e-5f), d2 = fmaxf(m2, 1e-5f);
    wsc[0] = 1.0f / d1; wsc[1] = d1; wsc[2] = 1.0f / d2; wsc[3] = d2;
  }
}

// ---------- 3. ternary weight quant (stored as bf16 {-1,0,1}) ----------
__global__ __launch_bounds__(256) void quant_w_kernel(const float* __restrict__ w,
    u16* __restrict__ q, const float* __restrict__ wsc, int widx, int n4) {
  float s = wsc[widx];
  for (int i = blockIdx.x * 256 + threadIdx.x; i < n4; i += gridDim.x * 256) {
    float4 v = ((const float4*)w)[i];
    ushort4 o;
    o.x = f2bf(fminf(fmaxf(rintf(v.x * s), -1.0f), 1.0f));
    o.y = f2bf(fminf(fmaxf(rintf(v.y * s), -1.0f), 1.0f));
    o.z = f2bf(fminf(fmaxf(rintf(v.z * s), -1.0f), 1.0f));
    o.w = f2bf(fminf(fmaxf(rintf(v.w * s), -1.0f), 1.0f));
    ((ushort4*)q)[i] = o;
  }
}

// ---------- 4. 256x256 8-phase GEMM (A[M][K] x B[N][K], bf16-int), T1+T2+T3+T4+T5 ----------
// EPI==0: dequant + exact GELU -> f16 store.  EPI==1: dequant -> f32 store.
// LDS: sm[buf][mat][256*64] bf16, XOR-swizzled in 16B blocks: kblk' = kblk ^ (row&7).
// Phases per K-tile (quadrant (mh,nh)): p0:(0,0) p1:(0,1) p2:(1,0) p3:(1,1).
// Stage schedule: p0: B-hi(t+1) | p1: A-lo(t+2) | p3: A-hi(t+2), B-lo(t+2).
// vmcnt(6) at each K-tile end (3 half-tiles in flight); vmcnt(0) before last tile.
template <int EPI>
__global__ __launch_bounds__(512, 2) void gemm8p(const u16* __restrict__ A,
    const u16* __restrict__ B, int N, int K, int gridN,
    const float* __restrict__ rowscale, const float* __restrict__ wsc,
    int widx, void* __restrict__ outp) {
  __shared__ __align__(16) u16 sm[2][2][16384];   // 128 KiB
  const int tid = threadIdx.x;
  const int lane = tid & 63;
  const int w = tid >> 6;
  const int wr = (w >> 2) * 64;    // row offset within a quadrant
  const int wc = (w & 3) * 32;     // col offset within a quadrant
  const int llo = lane & 15, lhi = lane >> 4;

  // T1: bijective XCD swizzle (gridDim.x % 8 == 0 here)
  const int nwg = gridDim.x;
  const int cpx = nwg >> 3;
  const int swz = (blockIdx.x & 7) * cpx + (blockIdx.x >> 3);
  const int bm = swz / gridN, bn = swz % gridN;

  const int NT = K >> 6;
  const size_t Abase = (size_t)(bm * 256) * K;
  const size_t Bbase = (size_t)(bn * 256) * K;

  // staging geometry: thread covers 16B blocks P0, P1 of a 128x64 half-tile
  const int P0 = tid, P1 = 512 + tid;
  const int r0s = P0 >> 3, r1s = P1 >> 3;
  const int kb0 = (P0 & 7) ^ (r0s & 7), kb1 = (P1 & 7) ^ (r1s & 7);

  auto stage = [&](int mat, int buf, int hf, int kt) {
    const u16* G = (mat == 0) ? A : B;
    size_t gb = ((mat == 0) ? Abase : Bbase) + (size_t)(hf * 128) * K + (size_t)kt * 64;
    u16* dst = &sm[buf][mat][hf * 8192];
    gload_lds16(G + gb + (size_t)r0s * K + kb0 * 8, dst + (size_t)P0 * 8);
    gload_lds16(G + gb + (size_t)r1s * K + kb1 * 8, dst + (size_t)P1 * 8);
  };

  bf16x8 a[4][2], b[2][2];
  auto readA = [&](int buf, int mh) {
    int rbase = mh * 128 + wr + llo;
#pragma unroll
    for (int m = 0; m < 4; m++) {
      int row = rbase + m * 16;
      int sw = row & 7;
#pragma unroll
      for (int ks = 0; ks < 2; ks++)
        a[m][ks] = *(const bf16x8*)&sm[buf][0][row * 64 + ((((ks << 2) + lhi) ^ sw) << 3)];
    }
  };
  auto readB = [&](int buf, int nh) {
    int rbase = nh * 128 + wc + llo;
#pragma unroll
    for (int n = 0; n < 2; n++) {
      int row = rbase + n * 16;
      int sw = row & 7;
#pragma unroll
      for (int ks = 0; ks < 2; ks++)
        b[n][ks] = *(const bf16x8*)&sm[buf][1][row * 64 + ((((ks << 2) + lhi) ^ sw) << 3)];
    }
  };

  f32x4 acc[4][4][2];
#pragma unroll
  for (int q = 0; q < 4; q++)
#pragma unroll
    for (int m = 0; m < 4; m++)
#pragma unroll
      for (int n = 0; n < 2; n++) acc[q][m][n] = (f32x4){0.f, 0.f, 0.f, 0.f};

  auto mmaq = [&](f32x4 (&c)[4][2]) {
    __builtin_amdgcn_s_setprio(1);
#pragma unroll
    for (int m = 0; m < 4; m++)
#pragma unroll
      for (int n = 0; n < 2; n++)
#pragma unroll
        for (int ks = 0; ks < 2; ks++)
          c[m][n] = __builtin_amdgcn_mfma_f32_16x16x32_bf16(a[m][ks], b[n][ks], c[m][n], 0, 0, 0);
    __builtin_amdgcn_s_setprio(0);
  };

  // prologue: A-lo0, A-hi0, B-lo0, B-hi0, A-lo1, A-hi1, B-lo1  (7 halves, 14 loads/wave... 2/wave each)
  stage(0, 0, 0, 0); stage(0, 0, 1, 0); stage(1, 0, 0, 0); stage(1, 0, 1, 0);
  stage(0, 1, 0, 1); stage(0, 1, 1, 1); stage(1, 1, 0, 1);
  asm volatile("s_waitcnt vmcnt(6)" ::: "memory");
  BAR();

  for (int kt = 0; kt < NT; kt++) {
    const int cur = kt & 1;
    // ---- p0: quadrant (0,0)
    readA(cur, 0); readB(cur, 0);
    if (kt + 1 < NT) stage(1, cur ^ 1, 1, kt + 1);     // B-hi(t+1)
    BAR();
    mmaq(acc[0]);
    BAR();
    // ---- p1: quadrant (0,1)  (A reused)
    readB(cur, 1);
    if (kt + 2 < NT) stage(0, cur, 0, kt + 2);         // A-lo(t+2), region retired at p0
    BAR();
    mmaq(acc[1]);
    BAR();
    // ---- p2: quadrant (1,0)
    readA(cur, 1); readB(cur, 0);
    BAR();
    mmaq(acc[2]);
    BAR();
    // ---- p3: quadrant (1,1)  (A reused)
    readB(cur, 1);
    if (kt + 2 < NT) { stage(0, cur, 1, kt + 2); stage(1, cur, 0, kt + 2); }  // A-hi, B-lo (t+2)
    BAR();
    mmaq(acc[3]);
    if (kt + 1 < NT) {
      if (kt + 2 == NT) asm volatile("s_waitcnt vmcnt(0)" ::: "memory");
      else              asm volatile("s_waitcnt vmcnt(6)" ::: "memory");
      BAR();
    }
  }

  // ---- epilogue
  float wdeq = wsc[widx];
#pragma unroll
  for (int q = 0; q < 4; q++) {
    int mh = q >> 1, nh = q & 1;
    int rbase = bm * 256 + mh * 128 + wr + lhi * 4;
    int cbase = bn * 256 + nh * 128 + wc + llo;
#pragma unroll
    for (int m = 0; m < 4; m++) {
#pragma unroll
      for (int reg = 0; reg < 4; reg++) {
        int r = rbase + m * 16 + reg;
        float deq = rowscale[r] * wdeq;
#pragma unroll
        for (int n = 0; n < 2; n++) {
          int c = cbase + n * 16;
          float val = acc[q][m][n][reg] * deq;
          if (EPI == 0) {
            float g = 0.5f * val * (1.0f + erff(val * 0.70710678118654752440f));
            ((u16*)outp)[(size_t)r * N + c] = f2h(g);
          } else {
            ((float*)outp)[(size_t)r * N + c] = val;
          }
        }
      }
    }
  }
}

// ---------- 5. per-row norm + quant of h (f16 in, bf16-int out, in place) ----------
__global__ __launch_bounds__(256) void quant_h_kernel(u16* __restrict__ h, float* __restrict__ invs) {
  const int D = 8192;
  int row = blockIdx.x, tid = threadIdx.x;
  u16* hr = h + (size_t)row * D;
  float v[32];
#pragma unroll
  for (int j = 0; j < 4; j++) {
    u16x8 u = *(const u16x8*)&hr[j * 2048 + tid * 8];
#pragma unroll
    for (int e = 0; e < 8; e++) v[j * 8 + e] = h2f(u[e]);
  }
  double ss = 0; float mx = 0.0f;
#pragma unroll
  for (int i = 0; i < 32; i++) { ss += (double)v[i] * v[i]; mx = fmaxf(mx, fabsf(v[i])); }
  __shared__ double sd[256]; __shared__ float sf[256];
  sd[tid] = ss; sf[tid] = mx; __syncthreads();
  for (int o = 128; o > 0; o >>= 1) {
    if (tid < o) { sd[tid] += sd[tid + o]; sf[tid] = fmaxf(sf[tid], sf[tid + o]); }
    __syncthreads();
  }
  __shared__ float bn, bs;
  if (tid == 0) {
    float n = fmaxf((float)sqrt(sd[0]), 1e-12f);
    float amax = sf[0] * (sqrtf((float)D) / n);
    float cl = fmaxf(amax, 1e-5f);
    bn = n; bs = 127.0f / cl;
    invs[row] = cl / 127.0f;
  }
  __syncthreads();
  float n = bn, s = bs, sq = sqrtf((float)D);
#pragma unroll
  for (int j = 0; j < 4; j++) {
    u16x8 q;
#pragma unroll
    for (int e = 0; e < 8; e++) {
      float xn = (v[j * 8 + e] / n) * sq;
      float r = rintf(xn * s);
      r = fminf(fmaxf(r, -128.0f), 127.0f);
      q[e] = f2bf(r);
    }
    *(u16x8*)&hr[j * 2048 + tid * 8] = q;
  }
}

// ---------- launch ----------
extern "C" void kernel_launch(void* const* d_in, const int* in_sizes, int n_in,
                              void* d_out, int out_size, void* d_ws, size_t ws_size,
                              hipStream_t stream) {
  const float* x  = (const float*)d_in[0];   // [4,2048,2048] f32
  const float* w1 = (const float*)d_in[1];   // [8192,2048]   f32
  const float* w2 = (const float*)d_in[2];   // [2048,8192]   f32

  char* ws = (char*)d_ws;
  u16*    qx     = (u16*)(ws + 0);             // 8192x2048 bf16  (32 MB)
  u16*    w1q    = (u16*)(ws + 33554432);      // 8192x2048 bf16  (32 MB)
  u16*    w2q    = (u16*)(ws + 67108864);      // 2048x8192 bf16  (32 MB)
  u16*    h      = (u16*)(ws + 100663296);     // 8192x8192 f16 -> bf16-int (128 MB)
  float*  invs_x = (float*)(ws + 234881024);   // 8192 f32
  float*  invs_h = (float*)(ws + 234913792);   // 8192 f32
  double* part   = (double*)(ws + 234946560);  // 1024 f64
  float*  wsc    = (float*)(ws + 234954752);   // 4 f32: {1/d1, d1, 1/d2, d2}

  quant_x_kernel<<<8192, 256, 0, stream>>>(x, qx, invs_x);
  absum_partial<<<512, 256, 0, stream>>>(w1, part, 4194304);
  absum_partial<<<512, 256, 0, stream>>>(w2, part + 512, 4194304);
  wscale_final<<<1, 256, 0, stream>>>(part, wsc);
  quant_w_kernel<<<2048, 256, 0, stream>>>(w1, w1q, wsc, 0, 4194304);
  quant_w_kernel<<<2048, 256, 0, stream>>>(w2, w2q, wsc, 2, 4194304);
  gemm8p<0><<<1024, 512, 0, stream>>>(qx, w1q, 8192, 2048, 32, invs_x, wsc, 1, (void*)h);
  quant_h_kernel<<<8192, 256, 0, stream>>>(h, invs_h);
  gemm8p<1><<<256, 512, 0, stream>>>(h, w2q, 2048, 8192, 8, invs_h, wsc, 3, d_out);
}

// Round 5
// 663.752 us; speedup vs baseline: 1.4275x; 1.0127x over previous
//
#include <hip/hip_runtime.h>
#include <hip/hip_bf16.h>
#include <hip/hip_fp16.h>

typedef __attribute__((ext_vector_type(4))) float f32x4;
typedef __attribute__((ext_vector_type(8))) __bf16 bf16x8;
typedef __attribute__((ext_vector_type(8))) unsigned short u16x8;
typedef unsigned int u32;
typedef unsigned short u16;

// ---------- helpers ----------
__device__ __forceinline__ void gload_lds16(const void* g, void* l) {
  __builtin_amdgcn_global_load_lds((const u32 __attribute__((address_space(1)))*)g,
                                   (u32 __attribute__((address_space(3)))*)l, 16, 0, 0);
}
__device__ __forceinline__ u16 f2bf(float f) {           // exact for small integers
  union { float f; u32 u; } c; c.f = f; return (u16)(c.u >> 16);
}
__device__ __forceinline__ float h2f(u16 u) { return __half2float(__ushort_as_half(u)); }
__device__ __forceinline__ u16  f2h(float f){ return __half_as_ushort(__float2half_rn(f)); }

// ---------- 1. per-token RMS-norm + absmax int8 quant of x (stored as bf16 ints) ----------
__global__ __launch_bounds__(256) void quant_x_kernel(const float* __restrict__ x,
    u16* __restrict__ qx, float* __restrict__ invs) {
  const int D = 2048;
  int row = blockIdx.x, tid = threadIdx.x;
  const float* xr = x + (size_t)row * D;
  float4 a = ((const float4*)xr)[tid * 2], b = ((const float4*)xr)[tid * 2 + 1];
  float v[8] = {a.x, a.y, a.z, a.w, b.x, b.y, b.z, b.w};
  double ss = 0; float mx = 0.0f;
#pragma unroll
  for (int i = 0; i < 8; i++) { ss += (double)v[i] * v[i]; mx = fmaxf(mx, fabsf(v[i])); }
  __shared__ double sd[256]; __shared__ float sf[256];
  sd[tid] = ss; sf[tid] = mx; __syncthreads();
  for (int o = 128; o > 0; o >>= 1) {
    if (tid < o) { sd[tid] += sd[tid + o]; sf[tid] = fmaxf(sf[tid], sf[tid + o]); }
    __syncthreads();
  }
  __shared__ float bn, bs;
  if (tid == 0) {
    float n = fmaxf((float)sqrt(sd[0]), 1e-12f);
    float amax = sf[0] * (sqrtf((float)D) / n);
    float cl = fmaxf(amax, 1e-5f);
    bn = n; bs = 127.0f / cl;
    invs[row] = cl / 127.0f;
  }
  __syncthreads();
  float n = bn, s = bs, sq = sqrtf((float)D);
  u16x8 q;
#pragma unroll
  for (int i = 0; i < 8; i++) {
    float xn = (v[i] / n) * sq;
    float r = rintf(xn * s);
    r = fminf(fmaxf(r, -128.0f), 127.0f);
    q[i] = f2bf(r);
  }
  *(u16x8*)&qx[(size_t)row * D + tid * 8] = q;
}

// ---------- 2. deterministic sum(|w|) partials ----------
__global__ __launch_bounds__(256) void absum_partial(const float* __restrict__ w,
    double* __restrict__ part, int n4) {
  int tid = threadIdx.x;
  double s = 0;
  for (int i = blockIdx.x * 256 + tid; i < n4; i += gridDim.x * 256) {
    float4 v = ((const float4*)w)[i];
    s += (double)fabsf(v.x) + (double)fabsf(v.y) + (double)fabsf(v.z) + (double)fabsf(v.w);
  }
  __shared__ double sd[256];
  sd[tid] = s; __syncthreads();
  for (int o = 128; o > 0; o >>= 1) { if (tid < o) sd[tid] += sd[tid + o]; __syncthreads(); }
  if (tid == 0) part[blockIdx.x] = sd[0];
}

__global__ __launch_bounds__(256) void wscale_final(const double* __restrict__ part,
    float* __restrict__ wsc) {
  int tid = threadIdx.x;
  __shared__ double sd[256];
  sd[tid] = part[tid] + part[tid + 256]; __syncthreads();
  for (int o = 128; o > 0; o >>= 1) { if (tid < o) sd[tid] += sd[tid + o]; __syncthreads(); }
  double s1 = sd[0]; __syncthreads();
  sd[tid] = part[512 + tid] + part[768 + tid]; __syncthreads();
  for (int o = 128; o > 0; o >>= 1) { if (tid < o) sd[tid] += sd[tid + o]; __syncthreads(); }
  if (tid == 0) {
    float m1 = (float)(s1 / 16777216.0);
    float m2 = (float)(sd[0] / 16777216.0);
    float d1 = fmaxf(m1, 1e-5f), d2 = fmaxf(m2, 1e-5f);
    wsc[0] = 1.0f / d1; wsc[1] = d1; wsc[2] = 1.0f / d2; wsc[3] = d2;
  }
}

// ---------- 3. ternary weight quant (stored as bf16 {-1,0,1}) ----------
__global__ __launch_bounds__(256) void quant_w_kernel(const float* __restrict__ w,
    u16* __restrict__ q, const float* __restrict__ wsc, int widx, int n4) {
  float s = wsc[widx];
  for (int i = blockIdx.x * 256 + threadIdx.x; i < n4; i += gridDim.x * 256) {
    float4 v = ((const float4*)w)[i];
    ushort4 o;
    o.x = f2bf(fminf(fmaxf(rintf(v.x * s), -1.0f), 1.0f));
    o.y = f2bf(fminf(fmaxf(rintf(v.y * s), -1.0f), 1.0f));
    o.z = f2bf(fminf(fmaxf(rintf(v.z * s), -1.0f), 1.0f));
    o.w = f2bf(fminf(fmaxf(rintf(v.w * s), -1.0f), 1.0f));
    ((ushort4*)q)[i] = o;
  }
}

// ---------- 4. 256x256 GEMM, batch-granular vmcnt ledger (order-robust) ----------
// A[M][K] x B[N][K], bf16-int. Wave grid 2Mx4N, per-wave tile 128x64, BK=64.
// Per tile: 24 ds_read_b128 at tile start -> lgkm(0)+barrier -> stage tile t+2
// (8 loads, any internal order) -> 64 MFMA -> vmcnt(8)+barrier (retires FULL
// batch t+1; intra-batch reorder by the MI scheduler is harmless since waits
// are batch-multiples and batches are separated by side-effecting asm).
// EPI==0: dequant + exact GELU -> f16 store.  EPI==1: dequant -> f32 store.
template <int EPI>
__global__ __launch_bounds__(512, 2) void gemm_tb(const u16* __restrict__ A,
    const u16* __restrict__ B, int N, int K, int gridN,
    const float* __restrict__ rowscale, const float* __restrict__ wsc,
    int widx, void* __restrict__ outp) {
  __shared__ __align__(16) u16 sm[2][2][16384];   // [buf][mat][256*64] = 128 KiB
  const int tid = threadIdx.x;
  const int lane = tid & 63, w = tid >> 6;
  const int wm = w >> 2, wn = w & 3;            // 2M x 4N wave grid
  const int llo = lane & 15, lhi = lane >> 4;
  const int sw = llo & 7;                        // read-side swizzle (row&7 == llo&7)

  // T1: bijective XCD swizzle (gridDim.x % 8 == 0)
  const int nwg = gridDim.x;
  const int cpx = nwg >> 3;
  const int swz = (blockIdx.x & 7) * cpx + (blockIdx.x >> 3);
  const int bm = swz / gridN, bn = swz % gridN;

  const int NT = K >> 6;
  const size_t Abase = (size_t)(bm * 256) * K;
  const size_t Bbase = (size_t)(bn * 256) * K;

  // staging: thread covers 16B blocks P0, P1 of a 128x64 half-tile (inverse-swizzled source)
  const int P0 = tid, P1 = 512 + tid;
  const int r0s = P0 >> 3, r1s = P1 >> 3;
  const int kb0 = (P0 & 7) ^ (r0s & 7), kb1 = (P1 & 7) ^ (r1s & 7);

  auto stage = [&](int mat, int buf, int hf, int kt) {
    const u16* G = (mat == 0) ? A : B;
    size_t gb = ((mat == 0) ? Abase : Bbase) + (size_t)(hf * 128) * K + (size_t)kt * 64;
    u16* dst = &sm[buf][mat][hf * 8192];
    gload_lds16(G + gb + (size_t)r0s * K + kb0 * 8, dst + (size_t)P0 * 8);
    gload_lds16(G + gb + (size_t)r1s * K + kb1 * 8, dst + (size_t)P1 * 8);
  };

  bf16x8 alo[4][2], ahi[4][2], blo[2][2], bhi[2][2];
  auto readA = [&](int buf, int half, bf16x8 (&dst)[4][2]) {
    int rbase = wm * 128 + half * 64 + llo;
#pragma unroll
    for (int f = 0; f < 4; f++)
#pragma unroll
      for (int ks = 0; ks < 2; ks++)
        dst[f][ks] = *(const bf16x8*)&sm[buf][0][(rbase + f * 16) * 64 + ((((ks << 2) + lhi) ^ sw) << 3)];
  };
  auto readB = [&](int buf, int half, bf16x8 (&dst)[2][2]) {
    int rbase = wn * 64 + half * 32 + llo;
#pragma unroll
    for (int f = 0; f < 2; f++)
#pragma unroll
      for (int ks = 0; ks < 2; ks++)
        dst[f][ks] = *(const bf16x8*)&sm[buf][1][(rbase + f * 16) * 64 + ((((ks << 2) + lhi) ^ sw) << 3)];
  };

  f32x4 acc[8][4];
#pragma unroll
  for (int m = 0; m < 8; m++)
#pragma unroll
    for (int n = 0; n < 4; n++) acc[m][n] = (f32x4){0.f, 0.f, 0.f, 0.f};

  auto mmaq = [&](bf16x8 (&av)[4][2], bf16x8 (&bv)[2][2], int mh, int nh) {
    __builtin_amdgcn_s_setprio(1);
#pragma unroll
    for (int m = 0; m < 4; m++)
#pragma unroll
      for (int n = 0; n < 2; n++)
#pragma unroll
        for (int ks = 0; ks < 2; ks++)
          acc[mh * 4 + m][nh * 2 + n] =
              __builtin_amdgcn_mfma_f32_16x16x32_bf16(av[m][ks], bv[n][ks],
                                                      acc[mh * 4 + m][nh * 2 + n], 0, 0, 0);
    __builtin_amdgcn_s_setprio(0);
  };

  // prologue: tile0 batch, fence, tile1 batch; retire tile0 as a whole.
  stage(0, 0, 0, 0); stage(0, 0, 1, 0); stage(1, 0, 0, 0); stage(1, 0, 1, 0);
  asm volatile("s_nop 0" ::: "memory");            // batch boundary fence
  stage(0, 1, 0, 1); stage(0, 1, 1, 1); stage(1, 1, 0, 1); stage(1, 1, 1, 1);
  asm volatile("s_waitcnt vmcnt(8)\n\ts_barrier" ::: "memory");   // tile0 fully in LDS

  for (int t = 0; t < NT; t++) {
    const int cur = t & 1;
    // all operands for tile t (24 ds_read_b128)
    readA(cur, 0, alo); readB(cur, 0, blo); readA(cur, 1, ahi); readB(cur, 1, bhi);
    // reads drained before any wave overwrites buf[cur]
    asm volatile("s_waitcnt lgkmcnt(0)\n\ts_barrier" ::: "memory");
    if (t + 2 < NT) {                               // stage tile t+2 (8 loads, any order)
      stage(0, cur, 0, t + 2); stage(1, cur, 0, t + 2);
      stage(0, cur, 1, t + 2); stage(1, cur, 1, t + 2);
    }
    mmaq(alo, blo, 0, 0);
    mmaq(alo, bhi, 0, 1);
    mmaq(ahi, bhi, 1, 1);
    mmaq(ahi, blo, 1, 0);
    if (t + 1 < NT) {                               // retire batch t+1 as a whole
      if (t + 2 < NT) asm volatile("s_waitcnt vmcnt(8)\n\ts_barrier" ::: "memory");
      else            asm volatile("s_waitcnt vmcnt(0)\n\ts_barrier" ::: "memory");
    }
  }

  // ---- epilogue
  float wdeq = wsc[widx];
#pragma unroll
  for (int mf = 0; mf < 8; mf++) {
#pragma unroll
    for (int reg = 0; reg < 4; reg++) {
      int r = bm * 256 + wm * 128 + mf * 16 + lhi * 4 + reg;
      float deq = rowscale[r] * wdeq;
#pragma unroll
      for (int nf = 0; nf < 4; nf++) {
        int c = bn * 256 + wn * 64 + nf * 16 + llo;
        float val = acc[mf][nf][reg] * deq;
        if (EPI == 0) {
          float g = 0.5f * val * (1.0f + erff(val * 0.70710678118654752440f));
          ((u16*)outp)[(size_t)r * N + c] = f2h(g);
        } else {
          ((float*)outp)[(size_t)r * N + c] = val;
        }
      }
    }
  }
}

// ---------- 5. per-row norm + quant of h (f16 in, bf16-int out, in place) ----------
__global__ __launch_bounds__(256) void quant_h_kernel(u16* __restrict__ h, float* __restrict__ invs) {
  const int D = 8192;
  int row = blockIdx.x, tid = threadIdx.x;
  u16* hr = h + (size_t)row * D;
  float v[32];
#pragma unroll
  for (int j = 0; j < 4; j++) {
    u16x8 u = *(const u16x8*)&hr[j * 2048 + tid * 8];
#pragma unroll
    for (int e = 0; e < 8; e++) v[j * 8 + e] = h2f(u[e]);
  }
  double ss = 0; float mx = 0.0f;
#pragma unroll
  for (int i = 0; i < 32; i++) { ss += (double)v[i] * v[i]; mx = fmaxf(mx, fabsf(v[i])); }
  __shared__ double sd[256]; __shared__ float sf[256];
  sd[tid] = ss; sf[tid] = mx; __syncthreads();
  for (int o = 128; o > 0; o >>= 1) {
    if (tid < o) { sd[tid] += sd[tid + o]; sf[tid] = fmaxf(sf[tid], sf[tid + o]); }
    __syncthreads();
  }
  __shared__ float bn, bs;
  if (tid == 0) {
    float n = fmaxf((float)sqrt(sd[0]), 1e-12f);
    float amax = sf[0] * (sqrtf((float)D) / n);
    float cl = fmaxf(amax, 1e-5f);
    bn = n; bs = 127.0f / cl;
    invs[row] = cl / 127.0f;
  }
  __syncthreads();
  float n = bn, s = bs, sq = sqrtf((float)D);
#pragma unroll
  for (int j = 0; j < 4; j++) {
    u16x8 q;
#pragma unroll
    for (int e = 0; e < 8; e++) {
      float xn = (v[j * 8 + e] / n) * sq;
      float r = rintf(xn * s);
      r = fminf(fmaxf(r, -128.0f), 127.0f);
      q[e] = f2bf(r);
    }
    *(u16x8*)&hr[j * 2048 + tid * 8] = q;
  }
}

// ---------- launch ----------
extern "C" void kernel_launch(void* const* d_in, const int* in_sizes, int n_in,
                              void* d_out, int out_size, void* d_ws, size_t ws_size,
                              hipStream_t stream) {
  const float* x  = (const float*)d_in[0];   // [4,2048,2048] f32
  const float* w1 = (const float*)d_in[1];   // [8192,2048]   f32
  const float* w2 = (const float*)d_in[2];   // [2048,8192]   f32

  char* ws = (char*)d_ws;
  u16*    qx     = (u16*)(ws + 0);             // 8192x2048 bf16  (32 MB)
  u16*    w1q    = (u16*)(ws + 33554432);      // 8192x2048 bf16  (32 MB)
  u16*    w2q    = (u16*)(ws + 67108864);      // 2048x8192 bf16  (32 MB)
  u16*    h      = (u16*)(ws + 100663296);     // 8192x8192 f16 -> bf16-int (128 MB)
  float*  invs_x = (float*)(ws + 234881024);   // 8192 f32
  float*  invs_h = (float*)(ws + 234913792);   // 8192 f32
  double* part   = (double*)(ws + 234946560);  // 1024 f64
  float*  wsc    = (float*)(ws + 234954752);   // 4 f32: {1/d1, d1, 1/d2, d2}

  quant_x_kernel<<<8192, 256, 0, stream>>>(x, qx, invs_x);
  absum_partial<<<512, 256, 0, stream>>>(w1, part, 4194304);
  absum_partial<<<512, 256, 0, stream>>>(w2, part + 512, 4194304);
  wscale_final<<<1, 256, 0, stream>>>(part, wsc);
  quant_w_kernel<<<2048, 256, 0, stream>>>(w1, w1q, wsc, 0, 4194304);
  quant_w_kernel<<<2048, 256, 0, stream>>>(w2, w2q, wsc, 2, 4194304);
  gemm_tb<0><<<1024, 512, 0, stream>>>(qx, w1q, 8192, 2048, 32, invs_x, wsc, 1, (void*)h);
  quant_h_kernel<<<8192, 256, 0, stream>>>(h, invs_h);
  gemm_tb<1><<<256, 512, 0, stream>>>(h, w2q, 2048, 8192, 8, invs_h, wsc, 3, d_out);
}

// Round 6
// 644.838 us; speedup vs baseline: 1.4693x; 1.0293x over previous
//
#include <hip/hip_runtime.h>
#include <hip/hip_bf16.h>
#include <hip/hip_fp16.h>

typedef __attribute__((ext_vector_type(4))) float f32x4;
typedef __attribute__((ext_vector_type(8))) __bf16 bf16x8;
typedef __attribute__((ext_vector_type(8))) unsigned short u16x8;
typedef unsigned int u32;
typedef unsigned short u16;

// ---------- helpers ----------
__device__ __forceinline__ void gload_lds16(const void* g, void* l) {
  __builtin_amdgcn_global_load_lds((const u32 __attribute__((address_space(1)))*)g,
                                   (u32 __attribute__((address_space(3)))*)l, 16, 0, 0);
}
__device__ __forceinline__ u16 f2bf(float f) {           // exact for small integers
  union { float f; u32 u; } c; c.f = f; return (u16)(c.u >> 16);
}
__device__ __forceinline__ float h2f(u16 u) { return __half2float(__ushort_as_half(u)); }
__device__ __forceinline__ u16  f2h(float f){ return __half_as_ushort(__float2half_rn(f)); }

// ---------- 1. per-token RMS-norm + absmax int8 quant of x (stored as bf16 ints) ----------
__global__ __launch_bounds__(256) void quant_x_kernel(const float* __restrict__ x,
    u16* __restrict__ qx, float* __restrict__ invs) {
  const int D = 2048;
  int row = blockIdx.x, tid = threadIdx.x;
  const float* xr = x + (size_t)row * D;
  float4 a = ((const float4*)xr)[tid * 2], b = ((const float4*)xr)[tid * 2 + 1];
  float v[8] = {a.x, a.y, a.z, a.w, b.x, b.y, b.z, b.w};
  double ss = 0; float mx = 0.0f;
#pragma unroll
  for (int i = 0; i < 8; i++) { ss += (double)v[i] * v[i]; mx = fmaxf(mx, fabsf(v[i])); }
  __shared__ double sd[256]; __shared__ float sf[256];
  sd[tid] = ss; sf[tid] = mx; __syncthreads();
  for (int o = 128; o > 0; o >>= 1) {
    if (tid < o) { sd[tid] += sd[tid + o]; sf[tid] = fmaxf(sf[tid], sf[tid + o]); }
    __syncthreads();
  }
  __shared__ float bn, bs;
  if (tid == 0) {
    float n = fmaxf((float)sqrt(sd[0]), 1e-12f);
    float amax = sf[0] * (sqrtf((float)D) / n);
    float cl = fmaxf(amax, 1e-5f);
    bn = n; bs = 127.0f / cl;
    invs[row] = cl / 127.0f;
  }
  __syncthreads();
  float n = bn, s = bs, sq = sqrtf((float)D);
  u16x8 q;
#pragma unroll
  for (int i = 0; i < 8; i++) {
    float xn = (v[i] / n) * sq;
    float r = rintf(xn * s);
    r = fminf(fmaxf(r, -128.0f), 127.0f);
    q[i] = f2bf(r);
  }
  *(u16x8*)&qx[(size_t)row * D + tid * 8] = q;
}

// ---------- 2. deterministic sum(|w|) partials ----------
__global__ __launch_bounds__(256) void absum_partial(const float* __restrict__ w,
    double* __restrict__ part, int n4) {
  int tid = threadIdx.x;
  double s = 0;
  for (int i = blockIdx.x * 256 + tid; i < n4; i += gridDim.x * 256) {
    float4 v = ((const float4*)w)[i];
    s += (double)fabsf(v.x) + (double)fabsf(v.y) + (double)fabsf(v.z) + (double)fabsf(v.w);
  }
  __shared__ double sd[256];
  sd[tid] = s; __syncthreads();
  for (int o = 128; o > 0; o >>= 1) { if (tid < o) sd[tid] += sd[tid + o]; __syncthreads(); }
  if (tid == 0) part[blockIdx.x] = sd[0];
}

__global__ __launch_bounds__(256) void wscale_final(const double* __restrict__ part,
    float* __restrict__ wsc) {
  int tid = threadIdx.x;
  __shared__ double sd[256];
  sd[tid] = part[tid] + part[tid + 256]; __syncthreads();
  for (int o = 128; o > 0; o >>= 1) { if (tid < o) sd[tid] += sd[tid + o]; __syncthreads(); }
  double s1 = sd[0]; __syncthreads();
  sd[tid] = part[512 + tid] + part[768 + tid]; __syncthreads();
  for (int o = 128; o > 0; o >>= 1) { if (tid < o) sd[tid] += sd[tid + o]; __syncthreads(); }
  if (tid == 0) {
    float m1 = (float)(s1 / 16777216.0);
    float m2 = (float)(sd[0] / 16777216.0);
    float d1 = fmaxf(m1, 1e-5f), d2 = fmaxf(m2, 1e-5f);
    wsc[0] = 1.0f / d1; wsc[1] = d1; wsc[2] = 1.0f / d2; wsc[3] = d2;
  }
}

// ---------- 3. ternary weight quant (stored as bf16 {-1,0,1}) ----------
__global__ __launch_bounds__(256) void quant_w_kernel(const float* __restrict__ w,
    u16* __restrict__ q, const float* __restrict__ wsc, int widx, int n4) {
  float s = wsc[widx];
  for (int i = blockIdx.x * 256 + threadIdx.x; i < n4; i += gridDim.x * 256) {
    float4 v = ((const float4*)w)[i];
    ushort4 o;
    o.x = f2bf(fminf(fmaxf(rintf(v.x * s), -1.0f), 1.0f));
    o.y = f2bf(fminf(fmaxf(rintf(v.y * s), -1.0f), 1.0f));
    o.z = f2bf(fminf(fmaxf(rintf(v.z * s), -1.0f), 1.0f));
    o.w = f2bf(fminf(fmaxf(rintf(v.w * s), -1.0f), 1.0f));
    ((ushort4*)q)[i] = o;
  }
}

// ---------- 4. 256x256 GEMM, interleaved quadrants on batch-granular vmcnt ledger ----------
// A[M][K] x B[N][K], bf16-int. Wave grid 2Mx4N, per-wave tile 128x64, BK=64.
// Per tile t: read ahi/bhi(t) | Q0 | lgkm(0)+bar | stage(t+2) | Q1 Q2 Q3 |
// vmcnt(8)+bar | read alo/blo(t+1).  Read bursts overlap the matrix-pipe drain
// of the preceding MFMA cluster; sync ledger identical to the passing r5 kernel
// (batch-multiple vmcnt waits, fused waitcnt+s_barrier asm; MFMA moves are
// register-only and compiler dep-tracked).
// EPI==0: dequant + exact GELU -> f16 store.  EPI==1: dequant -> f32 store.
template <int EPI>
__global__ __launch_bounds__(512, 2) void gemm_il(const u16* __restrict__ A,
    const u16* __restrict__ B, int N, int K, int gridN,
    const float* __restrict__ rowscale, const float* __restrict__ wsc,
    int widx, void* __restrict__ outp) {
  __shared__ __align__(16) u16 sm[2][2][16384];   // [buf][mat][256*64] = 128 KiB
  const int tid = threadIdx.x;
  const int lane = tid & 63, w = tid >> 6;
  const int wm = w >> 2, wn = w & 3;            // 2M x 4N wave grid
  const int llo = lane & 15, lhi = lane >> 4;
  const int sw = llo & 7;                        // read-side swizzle (row&7 == llo&7)

  // T1: bijective XCD swizzle (gridDim.x % 8 == 0)
  const int nwg = gridDim.x;
  const int cpx = nwg >> 3;
  const int swz = (blockIdx.x & 7) * cpx + (blockIdx.x >> 3);
  const int bm = swz / gridN, bn = swz % gridN;

  const int NT = K >> 6;
  const size_t Abase = (size_t)(bm * 256) * K;
  const size_t Bbase = (size_t)(bn * 256) * K;

  // staging: thread covers 16B blocks P0, P1 of a 128x64 half-tile (inverse-swizzled source)
  const int P0 = tid, P1 = 512 + tid;
  const int r0s = P0 >> 3, r1s = P1 >> 3;
  const int kb0 = (P0 & 7) ^ (r0s & 7), kb1 = (P1 & 7) ^ (r1s & 7);

  auto stage = [&](int mat, int buf, int hf, int kt) {
    const u16* G = (mat == 0) ? A : B;
    size_t gb = ((mat == 0) ? Abase : Bbase) + (size_t)(hf * 128) * K + (size_t)kt * 64;
    u16* dst = &sm[buf][mat][hf * 8192];
    gload_lds16(G + gb + (size_t)r0s * K + kb0 * 8, dst + (size_t)P0 * 8);
    gload_lds16(G + gb + (size_t)r1s * K + kb1 * 8, dst + (size_t)P1 * 8);
  };

  bf16x8 alo[4][2], ahi[4][2], blo[2][2], bhi[2][2];
  auto readA = [&](int buf, int half, bf16x8 (&dst)[4][2]) {
    int rbase = wm * 128 + half * 64 + llo;
#pragma unroll
    for (int f = 0; f < 4; f++)
#pragma unroll
      for (int ks = 0; ks < 2; ks++)
        dst[f][ks] = *(const bf16x8*)&sm[buf][0][(rbase + f * 16) * 64 + ((((ks << 2) + lhi) ^ sw) << 3)];
  };
  auto readB = [&](int buf, int half, bf16x8 (&dst)[2][2]) {
    int rbase = wn * 64 + half * 32 + llo;
#pragma unroll
    for (int f = 0; f < 2; f++)
#pragma unroll
      for (int ks = 0; ks < 2; ks++)
        dst[f][ks] = *(const bf16x8*)&sm[buf][1][(rbase + f * 16) * 64 + ((((ks << 2) + lhi) ^ sw) << 3)];
  };

  f32x4 acc[8][4];
#pragma unroll
  for (int m = 0; m < 8; m++)
#pragma unroll
    for (int n = 0; n < 4; n++) acc[m][n] = (f32x4){0.f, 0.f, 0.f, 0.f};

  auto mmaq = [&](bf16x8 (&av)[4][2], bf16x8 (&bv)[2][2], int mh, int nh) {
    __builtin_amdgcn_s_setprio(1);
#pragma unroll
    for (int m = 0; m < 4; m++)
#pragma unroll
      for (int n = 0; n < 2; n++)
#pragma unroll
        for (int ks = 0; ks < 2; ks++)
          acc[mh * 4 + m][nh * 2 + n] =
              __builtin_amdgcn_mfma_f32_16x16x32_bf16(av[m][ks], bv[n][ks],
                                                      acc[mh * 4 + m][nh * 2 + n], 0, 0, 0);
    __builtin_amdgcn_s_setprio(0);
  };

  // prologue: tile0 batch, fence, tile1 batch; retire tile0 as a whole.
  stage(0, 0, 0, 0); stage(0, 0, 1, 0); stage(1, 0, 0, 0); stage(1, 0, 1, 0);
  asm volatile("s_nop 0" ::: "memory");            // batch boundary fence
  stage(0, 1, 0, 1); stage(0, 1, 1, 1); stage(1, 1, 0, 1); stage(1, 1, 1, 1);
  asm volatile("s_waitcnt vmcnt(8)\n\ts_barrier" ::: "memory");   // tile0 fully in LDS
  readA(0, 0, alo); readB(0, 0, blo);              // first-half operands of tile 0

  for (int t = 0; t < NT; t++) {
    const int cur = t & 1;
    // remaining operands of tile t (12 ds_read_b128), in flight under Q0
    readA(cur, 1, ahi); readB(cur, 1, bhi);
    mmaq(alo, blo, 0, 0);                          // Q0 (lo,lo)
    __builtin_amdgcn_sched_barrier(0);
    // all reads of buf[cur] drained across all waves before anyone overwrites it
    asm volatile("s_waitcnt lgkmcnt(0)\n\ts_barrier" ::: "memory");
    if (t + 2 < NT) {                               // stage tile t+2 (8 loads, any order)
      stage(0, cur, 0, t + 2); stage(1, cur, 0, t + 2);
      stage(0, cur, 1, t + 2); stage(1, cur, 1, t + 2);
    }
    mmaq(alo, bhi, 0, 1);                          // Q1 (lo,hi)
    mmaq(ahi, bhi, 1, 1);                          // Q2 (hi,hi)
    mmaq(ahi, blo, 1, 0);                          // Q3 (hi,lo)
    __builtin_amdgcn_sched_barrier(0);
    if (t + 1 < NT) {                               // retire batch t+1 as a whole
      if (t + 2 < NT) asm volatile("s_waitcnt vmcnt(8)\n\ts_barrier" ::: "memory");
      else            asm volatile("s_waitcnt vmcnt(0)\n\ts_barrier" ::: "memory");
      // first-half operands of tile t+1, in flight under next tile's Q0
      readA(cur ^ 1, 0, alo); readB(cur ^ 1, 0, blo);
    }
  }

  // ---- epilogue
  float wdeq = wsc[widx];
#pragma unroll
  for (int mf = 0; mf < 8; mf++) {
#pragma unroll
    for (int reg = 0; reg < 4; reg++) {
      int r = bm * 256 + wm * 128 + mf * 16 + lhi * 4 + reg;
      float deq = rowscale[r] * wdeq;
#pragma unroll
      for (int nf = 0; nf < 4; nf++) {
        int c = bn * 256 + wn * 64 + nf * 16 + llo;
        float val = acc[mf][nf][reg] * deq;
        if (EPI == 0) {
          float g = 0.5f * val * (1.0f + erff(val * 0.70710678118654752440f));
          ((u16*)outp)[(size_t)r * N + c] = f2h(g);
        } else {
          ((float*)outp)[(size_t)r * N + c] = val;
        }
      }
    }
  }
}

// ---------- 5. per-row norm + quant of h (f16 in, bf16-int out, in place) ----------
__global__ __launch_bounds__(256) void quant_h_kernel(u16* __restrict__ h, float* __restrict__ invs) {
  const int D = 8192;
  int row = blockIdx.x, tid = threadIdx.x;
  u16* hr = h + (size_t)row * D;
  float v[32];
#pragma unroll
  for (int j = 0; j < 4; j++) {
    u16x8 u = *(const u16x8*)&hr[j * 2048 + tid * 8];
#pragma unroll
    for (int e = 0; e < 8; e++) v[j * 8 + e] = h2f(u[e]);
  }
  double ss = 0; float mx = 0.0f;
#pragma unroll
  for (int i = 0; i < 32; i++) { ss += (double)v[i] * v[i]; mx = fmaxf(mx, fabsf(v[i])); }
  __shared__ double sd[256]; __shared__ float sf[256];
  sd[tid] = ss; sf[tid] = mx; __syncthreads();
  for (int o = 128; o > 0; o >>= 1) {
    if (tid < o) { sd[tid] += sd[tid + o]; sf[tid] = fmaxf(sf[tid], sf[tid + o]); }
    __syncthreads();
  }
  __shared__ float bn, bs;
  if (tid == 0) {
    float n = fmaxf((float)sqrt(sd[0]), 1e-12f);
    float amax = sf[0] * (sqrtf((float)D) / n);
    float cl = fmaxf(amax, 1e-5f);
    bn = n; bs = 127.0f / cl;
    invs[row] = cl / 127.0f;
  }
  __syncthreads();
  float n = bn, s = bs, sq = sqrtf((float)D);
#pragma unroll
  for (int j = 0; j < 4; j++) {
    u16x8 q;
#pragma unroll
    for (int e = 0; e < 8; e++) {
      float xn = (v[j * 8 + e] / n) * sq;
      float r = rintf(xn * s);
      r = fminf(fmaxf(r, -128.0f), 127.0f);
      q[e] = f2bf(r);
    }
    *(u16x8*)&hr[j * 2048 + tid * 8] = q;
  }
}

// ---------- launch ----------
extern "C" void kernel_launch(void* const* d_in, const int* in_sizes, int n_in,
                              void* d_out, int out_size, void* d_ws, size_t ws_size,
                              hipStream_t stream) {
  const float* x  = (const float*)d_in[0];   // [4,2048,2048] f32
  const float* w1 = (const float*)d_in[1];   // [8192,2048]   f32
  const float* w2 = (const float*)d_in[2];   // [2048,8192]   f32

  char* ws = (char*)d_ws;
  u16*    qx     = (u16*)(ws + 0);             // 8192x2048 bf16  (32 MB)
  u16*    w1q    = (u16*)(ws + 33554432);      // 8192x2048 bf16  (32 MB)
  u16*    w2q    = (u16*)(ws + 67108864);      // 2048x8192 bf16  (32 MB)
  u16*    h      = (u16*)(ws + 100663296);     // 8192x8192 f16 -> bf16-int (128 MB)
  float*  invs_x = (float*)(ws + 234881024);   // 8192 f32
  float*  invs_h = (float*)(ws + 234913792);   // 8192 f32
  double* part   = (double*)(ws + 234946560);  // 1024 f64
  float*  wsc    = (float*)(ws + 234954752);   // 4 f32: {1/d1, d1, 1/d2, d2}

  quant_x_kernel<<<8192, 256, 0, stream>>>(x, qx, invs_x);
  absum_partial<<<512, 256, 0, stream>>>(w1, part, 4194304);
  absum_partial<<<512, 256, 0, stream>>>(w2, part + 512, 4194304);
  wscale_final<<<1, 256, 0, stream>>>(part, wsc);
  quant_w_kernel<<<2048, 256, 0, stream>>>(w1, w1q, wsc, 0, 4194304);
  quant_w_kernel<<<2048, 256, 0, stream>>>(w2, w2q, wsc, 2, 4194304);
  gemm_il<0><<<1024, 512, 0, stream>>>(qx, w1q, 8192, 2048, 32, invs_x, wsc, 1, (void*)h);
  quant_h_kernel<<<8192, 256, 0, stream>>>(h, invs_h);
  gemm_il<1><<<256, 512, 0, stream>>>(h, w2q, 2048, 8192, 8, invs_h, wsc, 3, d_out);
}